// Round 12
// baseline (740.015 us; speedup 1.0000x reference)
//
#include <hip/hip_runtime.h>

#define NCAM 6
#define FC   128
#define FH_  32
#define FW_  88
#define NPIX (FH_*FW_)        // 2816
#define PH   34
#define PW   92               // padded width (mult of 4 -> float4-aligned rows)
#define PPIX (PH*PW)          // 3128
#define ND   41
#define X3D  42               // 41 depth + 1 opacity planes
#define OUTC 128
#define GTOT (NCAM*NPIX)      // 16896
#define BEVH 100
#define BEVW 100
#define NPXB (BEVH*BEVW)      // 10000
#define NTILE 25              // 25x25 tiles of 4x4 px
#define NWORD 264             // 16896/64 mask words per tile
#define WCAP  70000           // worklist capacity (chunks)
#define CSIZE 64              // hits per chunk
#define CBLK  2048            // composite blocks (contiguous chunk ranges)

// ---- ws layout (float offsets). Total ~6.84M floats = 27.4 MB ----
#define SZA     (NCAM*FC*PPIX)           // 2402304
#define WS_CAM  0
#define WS_A    256                      // IMGP -> X2P -> hit lists (ushort)
#define WS_RB   (WS_A  + SZA)            // X1P -> colors
#define WS_X3   (WS_RB + SZA)            // depth+opacity planes -> masks+aux
#define WS_GS   (WS_X3 + NCAM*X3D*NPIX)  // gauss params 16896*8
#define WS_WL   (WS_GS + GTOT*8)         // worklist ints
#define WS_BASE (WS_WL + WCAP)           // per-chunk per-px bases WCAP*16

__device__ inline void inv3x3(const float* m, float* o) {
    float a=m[0],b=m[1],c=m[2],d=m[3],e=m[4],f=m[5],g=m[6],h=m[7],i=m[8];
    float A=e*i-f*h, B=c*h-b*i, C=b*f-c*e;
    float Dd=f*g-d*i, E=a*i-c*g, F=c*d-a*f;
    float Gg=d*h-e*g, H=b*g-a*h, I=a*e-b*d;
    float r = 1.0f/(a*A + b*Dd + c*Gg);
    o[0]=A*r; o[1]=B*r; o[2]=C*r; o[3]=Dd*r; o[4]=E*r; o[5]=F*r;
    o[6]=Gg*r; o[7]=H*r; o[8]=I*r;
}

__global__ void cam_consts_kernel(const float* __restrict__ rot, const float* __restrict__ tr,
                                  const float* __restrict__ intr, const float* __restrict__ prot,
                                  const float* __restrict__ ptr_, float* __restrict__ cam) {
    int n = threadIdx.x;
    if (n >= NCAM) return;
    float M1[9], Ki[9];
    inv3x3(prot + n*9, M1);
    inv3x3(intr + n*9, Ki);
    const float* R = rot + n*9;
    float* c = cam + n*24;
    for (int i=0;i<9;i++) c[i] = M1[i];
    for (int i=0;i<3;i++) c[9+i] = ptr_[n*3+i];
    for (int i=0;i<3;i++)
        for (int j=0;j<3;j++)
            c[12+i*3+j] = R[i*3+0]*Ki[0+j] + R[i*3+1]*Ki[3+j] + R[i*3+2]*Ki[6+j];
    for (int i=0;i<3;i++) c[21+i] = tr[n*3+i];
}

__global__ __launch_bounds__(256) void pad_input_kernel(const float* __restrict__ src,
                                                        float* __restrict__ dst) {
    int idx = blockIdx.x*256 + threadIdx.x;
    int plane = idx / NPIX, px = idx - plane*NPIX;
    int y = px / FW_, x = px - y*FW_;
    dst[(size_t)plane*PPIX + (y+1)*PW + (x+1)] = src[idx];
}

// split-K-in-block 3x3 conv + folded BN + ReLU. 512 threads: half ks=0 does
// ci 0..63, half ks=1 does ci 64..127 (each with 4co x 4px, float4+float2
// window loads = 144 FMA : 6 loads per ci). Halves combined via LDS (stride-1,
// conflict-free), BN+ReLU fused in epilogue. Grid (6,32,3) x 8 waves = 56% fill.
__global__ __launch_bounds__(512) void conv3x3_sk_kernel(
        const float* __restrict__ in, float* __restrict__ out, const float* __restrict__ w,
        const float* __restrict__ cb, const float* __restrict__ bg, const float* __restrict__ bb,
        const float* __restrict__ bm, const float* __restrict__ bv) {
    __shared__ float sacc[16][256];      // [co*4+p][quad-thread] = 16 KB
    const int n   = blockIdx.x;
    const int co0 = blockIdx.y * 4;
    const int t   = threadIdx.x;         // 0..511
    const int ks  = t >> 8;              // k-slice 0/1
    const int tq  = t & 255;
    const int qid = blockIdx.z * 256 + tq;   // 0..767, 704 valid
    const bool valid = (qid < 704);
    const int y  = valid ? (qid / 22) : 0;
    const int x0 = valid ? ((qid - y*22) * 4) : 0;
    float acc[4][4] = {};
    {
        const float* ip = in + (size_t)(n*FC + ks*64)*PPIX + y*PW + x0;
        const float* wb = w + (size_t)co0*FC*9 + (size_t)ks*64*9;
        for (int ci=0; ci<64; ++ci) {
            float v[3][6];
            #pragma unroll
            for (int r=0;r<3;r++) {
                float4 q4 = *(const float4*)(ip + r*PW);
                float2 q2 = *(const float2*)(ip + r*PW + 4);
                v[r][0]=q4.x; v[r][1]=q4.y; v[r][2]=q4.z; v[r][3]=q4.w; v[r][4]=q2.x; v[r][5]=q2.y;
            }
            #pragma unroll
            for (int c=0;c<4;c++) {
                const float* wr = wb + (size_t)c*FC*9 + ci*9;   // wave-uniform -> s_load
                float w00=wr[0],w01=wr[1],w02=wr[2],w10=wr[3],w11=wr[4],
                      w12=wr[5],w20=wr[6],w21=wr[7],w22=wr[8];
                #pragma unroll
                for (int p=0;p<4;p++) {
                    float a = acc[c][p];
                    a = fmaf(w00, v[0][p], a); a = fmaf(w01, v[0][p+1], a); a = fmaf(w02, v[0][p+2], a);
                    a = fmaf(w10, v[1][p], a); a = fmaf(w11, v[1][p+1], a); a = fmaf(w12, v[1][p+2], a);
                    a = fmaf(w20, v[2][p], a); a = fmaf(w21, v[2][p+1], a); a = fmaf(w22, v[2][p+2], a);
                    acc[c][p] = a;
                }
            }
            ip += PPIX;
        }
    }
    if (ks == 1) {
        #pragma unroll
        for (int c=0;c<4;c++)
            #pragma unroll
            for (int p=0;p<4;p++) sacc[c*4+p][tq] = acc[c][p];
    }
    __syncthreads();
    if (ks == 0 && valid) {
        const int po = (y+1)*PW + (x0+1);
        #pragma unroll
        for (int c=0;c<4;c++) {
            float s  = bg[co0+c] * rsqrtf(bv[co0+c] + 1e-3f);
            float sh = (cb[co0+c] - bm[co0+c]) * s + bb[co0+c];
            float* op = out + ((size_t)n*FC + co0 + c)*PPIX + po;
            #pragma unroll
            for (int p=0;p<4;p++) {
                float tot = acc[c][p] + sacc[c*4+p][tq];
                op[p] = fmaxf(fmaf(tot, s, sh), 0.0f);
            }
        }
    }
}

// 1x1 conv: grid (NCAM, 11 px-chunks, 22 co-groups of 8). acc[8] fully unrolled
// (stays in VGPRs), weights wave-uniform -> s_loads.
__global__ __launch_bounds__(256) void conv1x1_kernel(const float* __restrict__ in,
        float* __restrict__ x3d, float* __restrict__ colors,
        const float* __restrict__ w, const float* __restrict__ b) {
    const int n   = blockIdx.x;
    const int px  = blockIdx.y * 256 + threadIdx.x;
    const int co0 = blockIdx.z * 8;                  // 0..168
    const int y   = px / FW_, x = px - y*FW_;
    const int pp  = (y+1)*PW + (x+1);
    const float* wr[8];
    float acc[8];
    #pragma unroll
    for (int k=0;k<8;k++) {
        int co = min(co0 + k, 169);                  // clamp avoids OOB reads (stores guarded)
        wr[k]  = w + (size_t)co*FC;
        acc[k] = b[co];
    }
    const float* ip = in + (size_t)n*FC*PPIX + pp;
    #pragma unroll 4
    for (int ci=0; ci<FC; ++ci) {
        float v = ip[(size_t)ci*PPIX];
        #pragma unroll
        for (int k=0;k<8;k++) acc[k] = fmaf(wr[k][ci], v, acc[k]);
    }
    #pragma unroll
    for (int k=0;k<8;k++) {
        int co = co0 + k;
        if (co < X3D)
            x3d[((size_t)n*X3D + co)*NPIX + px] = acc[k];
        else if (co < 170)
            colors[(((size_t)(n*NPIX + px)) << 7) + (co - X3D)] = acc[k];
    }
}

// per-gaussian: softmax moments, splat params {my,mx,A,2B,C,qm,ri,rj}
__global__ __launch_bounds__(256) void moments_kernel(const float* __restrict__ x3,
        const float* __restrict__ cam, float* __restrict__ gauss, float* __restrict__ ng) {
    int gi = blockIdx.x*256 + threadIdx.x;
    int n  = gi / NPIX;
    int p  = gi - n*NPIX;
    int h  = p / FW_, xp = p - h*FW_;
    const float* cc = cam + n*24;
    float u = xp * (703.0f/87.0f);
    float v = h  * (255.0f/31.0f);
    float fx = u - cc[9], fy = v - cc[10], fz = -cc[11];
    float p0x = cc[0]*fx + cc[1]*fy + cc[2]*fz;
    float p0y = cc[3]*fx + cc[4]*fy + cc[5]*fz;
    float p0z = cc[6]*fx + cc[7]*fy + cc[8]*fz;
    const float* lg = x3 + (size_t)n*X3D*NPIX + p;

    float mxl = -1e30f;
    for (int d=0; d<ND; ++d) mxl = fmaxf(mxl, lg[(size_t)d*NPIX]);
    float s=0.f, sgx=0.f, sgy=0.f;
    for (int d=0; d<ND; ++d) {
        float e  = __expf(lg[(size_t)d*NPIX] - mxl);
        float dz = 4.0f + (float)d;
        float pz = p0z + dz*cc[8];
        float px = (p0x + dz*cc[2]) * pz;
        float py = (p0y + dz*cc[5]) * pz;
        float gx = cc[12]*px + cc[13]*py + cc[14]*pz + cc[21];
        float gy = cc[15]*px + cc[16]*py + cc[17]*pz + cc[22];
        s += e; sgx += e*gx; sgy += e*gy;
    }
    float inv_s = 1.0f/s;
    float mex = sgx*inv_s, mey = sgy*inv_s;
    float cxx=0.f, cxy=0.f, cyy=0.f;
    for (int d=0; d<ND; ++d) {
        float e  = __expf(lg[(size_t)d*NPIX] - mxl);
        float dz = 4.0f + (float)d;
        float pz = p0z + dz*cc[8];
        float px = (p0x + dz*cc[2]) * pz;
        float py = (p0y + dz*cc[5]) * pz;
        float gx = cc[12]*px + cc[13]*py + cc[14]*pz + cc[21];
        float gy = cc[15]*px + cc[16]*py + cc[17]*pz + cc[22];
        float dxv = gx - mex, dyv = gy - mey;
        cxx += e*dxv*dxv; cxy += e*dxv*dyv; cyy += e*dyv*dyv;
    }
    const float k9 = inv_s * (1.0f/9.0f);
    cxx *= k9; cxy *= k9; cyy *= k9;

    float lo = lg[(size_t)ND*NPIX];
    float op = 1.0f/(1.0f + __expf(-lo));
    bool mask = op > 0.05f;

    const float SC = 0.02f, SH = 50.0f, SW = 50.0f;
    float my = -SH*(mey*SC) + 50.0f;
    float mx = -SW*(mex*SC) + 50.0f;
    float a  = SH*SH*(cyy*SC*SC) + 0.3f;
    float b  = SH*SW*(cxy*SC*SC);
    float c  = SW*SW*(cxx*SC*SC) + 0.3f;
    float det = a*c - b*b;
    bool valid = mask && (det > 0.0f);
    float A, B2, C, qm, ri, rj;
    if (valid) {
        float idet = 1.0f/det;
        A = c*idet; B2 = -2.0f*b*idet; C = a*idet;
        qm = 2.0f*__logf(255.0f*op);
        ri = sqrtf(qm*a); rj = sqrtf(qm*c);
    } else { A=B2=C=0.f; qm=-1.0f; ri=-1e30f; rj=-1e30f; }
    float* gp = gauss + (size_t)gi*8;
    gp[0]=my; gp[1]=mx; gp[2]=A; gp[3]=B2; gp[4]=C; gp[5]=qm; gp[6]=ri; gp[7]=rj;

    unsigned long long bal = __ballot(mask);
    if ((threadIdx.x & 63) == 0) atomicAdd(ng, (float)__popcll(bal));
}

// exact per-row ellipse interval culling -> tile bitmasks
__global__ __launch_bounds__(256) void build_masks_kernel(const float* __restrict__ gauss,
        unsigned long long* __restrict__ masks) {
    const int g = blockIdx.x*256 + threadIdx.x;
    const float4 g0 = *(const float4*)(gauss + ((size_t)g << 3));      // my,mx,A,2B
    const float4 g1 = *(const float4*)(gauss + ((size_t)g << 3) + 4);  // C,qm,ri,rj
    if (g1.y < 0.0f) return;
    const float my = g0.x, mx = g0.y, A = g0.z, B = 0.5f*g0.w, C = g1.x, qm = g1.y, ri = g1.z;
    const float invC = 1.0f / C;
    const float k2 = C*A - B*B;          // > 0
    int ti0 = max(0, (int)floorf((my - ri) * 0.25f));
    int ti1 = min(NTILE-1, (int)floorf((my + ri) * 0.25f));
    const int wi = g >> 6;
    const unsigned long long bit = 1ull << (g & 63);
    for (int ti = ti0; ti <= ti1; ++ti) {
        float jmn = 1e30f, jmx = -1e30f;
        #pragma unroll
        for (int r = 0; r < 4; ++r) {
            int i = 4*ti + r;
            if (i < 0 || i > 99) continue;
            float di = (float)i - my;
            float disc = C*qm - k2*di*di;
            if (disc < 0.0f) continue;
            float sd = sqrtf(disc);
            float jc = -B*di;
            jmn = fminf(jmn, (jc - sd)*invC + mx);
            jmx = fmaxf(jmx, (jc + sd)*invC + mx);
        }
        if (jmx < jmn) continue;
        int jl = max(0, (int)ceilf(jmn));
        int jh = min(99, (int)floorf(jmx));
        if (jl > jh) continue;
        for (int tj = (jl >> 2); tj <= (jh >> 2); ++tj)
            atomicOr(&masks[(size_t)(ti*NTILE + tj)*NWORD + wi], bit);
    }
}

// per-tile hit count
__global__ __launch_bounds__(256) void cnt_kernel(const unsigned long long* __restrict__ masks,
                                                  int* __restrict__ cnt) {
    __shared__ int sc;
    const int tile = blockIdx.x, t = threadIdx.x;
    if (t == 0) sc = 0;
    __syncthreads();
    if (t < NWORD) atomicAdd(&sc, __popcll(masks[(size_t)tile*NWORD + t]));
    __syncthreads();
    if (t == 0) cnt[tile] = sc;
}

// parallel exclusive scans over 625 tiles (single 640-thread block, shfl scan)
__global__ __launch_bounds__(640) void scan_kernel(const int* __restrict__ cnt,
        int* __restrict__ off, int* __restrict__ choff, int* __restrict__ nwork) {
    __shared__ int wsum[16], wsum2[16];
    const int t = threadIdx.x;              // 0..639, 10 waves
    const int lane = t & 63, wv = t >> 6;
    int c  = (t < NTILE*NTILE) ? cnt[t] : 0;
    int ch = (c + CSIZE-1) >> 6;
    int v = c, v2 = ch;
    #pragma unroll
    for (int o = 1; o < 64; o <<= 1) {
        int u  = __shfl_up(v,  (unsigned)o, 64);
        int u2 = __shfl_up(v2, (unsigned)o, 64);
        if (lane >= o) { v += u; v2 += u2; }
    }
    if (lane == 63) { wsum[wv] = v; wsum2[wv] = v2; }
    __syncthreads();
    int pre = 0, pre2 = 0;
    for (int w2 = 0; w2 < wv; ++w2) { pre += wsum[w2]; pre2 += wsum2[w2]; }
    int inc = v + pre, inc2 = v2 + pre2;
    if (t < NTILE*NTILE) { off[t] = inc - c; choff[t] = inc2 - ch; }
    if (t == NTILE*NTILE - 1) {
        off[NTILE*NTILE] = inc;
        choff[NTILE*NTILE] = inc2;
        nwork[0] = (inc2 > WCAP) ? WCAP : inc2;
    }
}

// expand bitmasks -> dense ordered hit lists + chunk worklist
__global__ __launch_bounds__(256) void fill_kernel(const unsigned long long* __restrict__ masks,
        const int* __restrict__ cnt, const int* __restrict__ off, const int* __restrict__ choff,
        unsigned short* __restrict__ list, int* __restrict__ wl) {
    __shared__ unsigned long long sw[NWORD];
    __shared__ int wpre[NWORD];
    const int tile = blockIdx.x, t = threadIdx.x;
    if (t < NWORD) sw[t] = masks[(size_t)tile*NWORD + t];
    __syncthreads();
    if (t == 0) {
        int run = 0;
        for (int w2 = 0; w2 < NWORD; ++w2) { wpre[w2] = run; run += __popcll(sw[w2]); }
    }
    __syncthreads();
    if (t < NWORD) {
        unsigned long long m = sw[t];
        int pos = off[tile] + wpre[t], base = t << 6;
        while (m) { int b = __builtin_ctzll(m); m &= m - 1; list[pos++] = (unsigned short)(base + b); }
    }
    int nch = (cnt[tile] + CSIZE-1)/CSIZE;
    int c0 = choff[tile];
    if (t < nch && c0 + t < WCAP) wl[c0 + t] = (tile << 9) | t;
}

__device__ inline float eval_alpha(const float4 g0, const float4 g1, float fi, float fj) {
    float dI = fi - g0.x, dJ = fj - g0.y;
    float q = dI*(g0.z*dI + g0.w*dJ) + g1.x*dJ*dJ;     // g0.w = 2B
    if (q < 0.0f || q > g1.y) return 0.0f;
    return fminf(0.99f, 0.003921568627f * __expf(0.5f*(g1.y - q)));
}

// per chunk: per-px sums of log(1-alpha) -> BASE[e][px] (pre-prefix)
__global__ __launch_bounds__(256) void chunk_sums_kernel(const float* __restrict__ gauss,
        const unsigned short* __restrict__ list, const int* __restrict__ cnt,
        const int* __restrict__ off, const int* __restrict__ wl, const int* __restrict__ nwork,
        float* __restrict__ base) {
    const int nw = nwork[0];
    const int t = threadIdx.x;
    const int px = t & 15, kg = t >> 4;
    __shared__ unsigned short slist[CSIZE];
    __shared__ float red[16][17];
    for (int e = blockIdx.x; e < nw; e += gridDim.x) {
        int v = wl[e], tile = v >> 9, c = v & 511;
        int hbase = off[tile] + (c << 6);
        int nh = min(CSIZE, cnt[tile] - (c << 6));
        if (t < nh) slist[t] = list[hbase + t];
        __syncthreads();
        const int i0 = (tile / NTILE) * 4, j0 = (tile % NTILE) * 4;
        const float fi = (float)(i0 + (px >> 2)), fj = (float)(j0 + (px & 3));
        float s = 0.0f;
        for (int k = kg; k < nh; k += 16) {
            int g = slist[k];
            float4 g0 = *(const float4*)(gauss + ((size_t)g << 3));
            float4 g1 = *(const float4*)(gauss + ((size_t)g << 3) + 4);
            float a = eval_alpha(g0, g1, fi, fj);
            if (a > 0.0f) s += __logf(1.0f - a);
        }
        red[kg][px] = s;
        __syncthreads();
        if (t < 16) {
            float acc = 0.0f;
            #pragma unroll
            for (int k2 = 0; k2 < 16; ++k2) acc += red[k2][t];
            base[(size_t)e*16 + t] = acc;
        }
        __syncthreads();
    }
}

// per tile: exclusive prefix of chunk sums (in place) -> chunk-start log-T bases
__global__ __launch_bounds__(256) void chunk_prefix_kernel(const int* __restrict__ choff,
                                                           float* __restrict__ base) {
    __shared__ float part[16][17];
    const int tile = blockIdx.x, t = threadIdx.x;
    const int c0 = choff[tile], nch = choff[tile+1] - c0;
    if (nch == 0) return;
    const int px = t & 15, cg = t >> 4;
    const int L16 = (nch + 15) >> 4;
    const int a0 = cg*L16, a1 = min(nch, a0 + L16);
    float s = 0.0f;
    for (int c = a0; c < a1; ++c) s += base[(size_t)(c0 + c)*16 + px];
    part[cg][px] = s;
    __syncthreads();
    if (t < 16) {
        float run = 0.0f;
        #pragma unroll
        for (int k = 0; k < 16; ++k) { float tmp = part[k][t]; part[k][t] = run; run += tmp; }
    }
    __syncthreads();
    float run = part[cg][px];
    for (int c = a0; c < a1; ++c) {
        size_t idx = (size_t)(c0 + c)*16 + px;
        float tmp = base[idx];
        base[idx] = run;
        run += tmp;
    }
}

// split-phase composite over CONTIGUOUS chunk ranges; accumulators flushed to
// global atomics only on tile change (worklist is tile-major).
__global__ __launch_bounds__(256) void composite_kernel(const float* __restrict__ gauss,
        const float* __restrict__ colors, const unsigned short* __restrict__ list,
        const int* __restrict__ cnt, const int* __restrict__ off, const int* __restrict__ wl,
        const int* __restrict__ nwork, const float* __restrict__ base, float* __restrict__ out) {
    const int nw = nwork[0];
    const int t = threadIdx.x;
    const int lane = t & 63;
    const int e_px = t >> 4, e_kg = t & 15;      // eval mapping
    const int a_cs4 = t & 31, a_pxq = t >> 5;    // accum: 4 channels, 2 pixels
    __shared__ unsigned short slist[CSIZE];
    __shared__ float s_w[CSIZE][17];
    const int per = (nw + CBLK - 1) / CBLK;
    int e0 = blockIdx.x * per;
    if (e0 >= nw) return;
    int e1 = min(nw, e0 + per);

    float4 acc0 = make_float4(0.f,0.f,0.f,0.f);
    float4 acc1 = make_float4(0.f,0.f,0.f,0.f);
    int cur_tile = wl[e0] >> 9;
    int cur_i0 = (cur_tile / NTILE) * 4, cur_j0 = (cur_tile % NTILE) * 4;

    for (int e = e0; e < e1; ++e) {
        int v = wl[e], tile = v >> 9, c = v & 511;
        if (tile != cur_tile) {
            const int pix0 = (cur_i0 + (a_pxq >> 2)) * BEVW + cur_j0 + (a_pxq & 3);
            const int pix1 = pix0 + 2 * BEVW;
            float* op = out + (size_t)(a_cs4 << 2) * NPXB;
            atomicAdd(op + 0*NPXB + pix0, acc0.x); atomicAdd(op + 1*NPXB + pix0, acc0.y);
            atomicAdd(op + 2*NPXB + pix0, acc0.z); atomicAdd(op + 3*NPXB + pix0, acc0.w);
            atomicAdd(op + 0*NPXB + pix1, acc1.x); atomicAdd(op + 1*NPXB + pix1, acc1.y);
            atomicAdd(op + 2*NPXB + pix1, acc1.z); atomicAdd(op + 3*NPXB + pix1, acc1.w);
            acc0 = make_float4(0.f,0.f,0.f,0.f);
            acc1 = make_float4(0.f,0.f,0.f,0.f);
            cur_tile = tile;
            cur_i0 = (tile / NTILE) * 4; cur_j0 = (tile % NTILE) * 4;
        }
        int hbase = off[cur_tile] + (c << 6);
        int nh = min(CSIZE, cnt[cur_tile] - (c << 6));
        if (t < nh) slist[t] = list[hbase + t];
        __syncthreads();
        // ---- phase E: eval each (hit,px) once + 16-lane segmented scan ----
        {
            const float fi = (float)(cur_i0 + (e_px >> 2)), fj = (float)(cur_j0 + (e_px & 3));
            const int k0 = e_kg << 2;
            float a4[4]; float lsum = 0.0f;
            #pragma unroll
            for (int i = 0; i < 4; ++i) {
                int k = k0 + i;
                float a = 0.0f;
                if (k < nh) {
                    int g = slist[k];
                    float4 g0 = *(const float4*)(gauss + ((size_t)g << 3));
                    float4 g1 = *(const float4*)(gauss + ((size_t)g << 3) + 4);
                    a = eval_alpha(g0, g1, fi, fj);
                }
                a4[i] = a;
                if (a > 0.0f) lsum += __logf(1.0f - a);
            }
            float s = lsum;
            #pragma unroll
            for (int o = 1; o < 16; o <<= 1) {
                float u = __shfl_up(s, (unsigned)o, 64);
                if ((lane & 15) >= o) s += u;
            }
            float T = __expf(base[(size_t)e*16 + e_px] + (s - lsum));
            #pragma unroll
            for (int i = 0; i < 4; ++i) {
                float wv = a4[i] * T; T -= wv;
                s_w[k0 + i][e_px] = wv;
            }
        }
        __syncthreads();
        // ---- phase A: dependency-free accumulation into registers ----
        for (int k = 0; k < nh; ++k) {
            int g = slist[k];
            float w0 = s_w[k][a_pxq];
            float w1 = s_w[k][a_pxq + 8];
            float4 cl = *(const float4*)(colors + ((size_t)g << 7) + (a_cs4 << 2));
            acc0.x = fmaf(w0, cl.x, acc0.x); acc0.y = fmaf(w0, cl.y, acc0.y);
            acc0.z = fmaf(w0, cl.z, acc0.z); acc0.w = fmaf(w0, cl.w, acc0.w);
            acc1.x = fmaf(w1, cl.x, acc1.x); acc1.y = fmaf(w1, cl.y, acc1.y);
            acc1.z = fmaf(w1, cl.z, acc1.z); acc1.w = fmaf(w1, cl.w, acc1.w);
        }
        __syncthreads();
    }
    // final flush
    const int pix0 = (cur_i0 + (a_pxq >> 2)) * BEVW + cur_j0 + (a_pxq & 3);
    const int pix1 = pix0 + 2 * BEVW;
    float* op = out + (size_t)(a_cs4 << 2) * NPXB;
    atomicAdd(op + 0*NPXB + pix0, acc0.x); atomicAdd(op + 1*NPXB + pix0, acc0.y);
    atomicAdd(op + 2*NPXB + pix0, acc0.z); atomicAdd(op + 3*NPXB + pix0, acc0.w);
    atomicAdd(op + 0*NPXB + pix1, acc1.x); atomicAdd(op + 1*NPXB + pix1, acc1.y);
    atomicAdd(op + 2*NPXB + pix1, acc1.z); atomicAdd(op + 3*NPXB + pix1, acc1.w);
}

extern "C" void kernel_launch(void* const* d_in, const int* in_sizes, int n_in,
                              void* d_out, int out_size, void* d_ws, size_t ws_size,
                              hipStream_t stream) {
    const float* rot  = (const float*)d_in[0];
    const float* tr   = (const float*)d_in[1];
    const float* intr = (const float*)d_in[2];
    const float* prot = (const float*)d_in[3];
    const float* ptr_ = (const float*)d_in[4];
    const float* img  = (const float*)d_in[5];
    const float* c1w  = (const float*)d_in[6];  const float* c1b = (const float*)d_in[7];
    const float* b1g  = (const float*)d_in[8];  const float* b1b = (const float*)d_in[9];
    const float* b1m  = (const float*)d_in[10]; const float* b1v = (const float*)d_in[11];
    const float* c2w  = (const float*)d_in[12]; const float* c2b = (const float*)d_in[13];
    const float* b2g  = (const float*)d_in[14]; const float* b2b = (const float*)d_in[15];
    const float* b2m  = (const float*)d_in[16]; const float* b2v = (const float*)d_in[17];
    const float* c3w  = (const float*)d_in[18]; const float* c3b = (const float*)d_in[19];
    float* out = (float*)d_out;
    float* ws  = (float*)d_ws;
    float* CAM = ws + WS_CAM;
    float* RA  = ws + WS_A;    // IMGP -> X2P -> lists
    float* RB  = ws + WS_RB;   // X1P -> colors
    float* X3B = ws + WS_X3;   // planes -> masks+aux
    float* GS  = ws + WS_GS;
    int*   WL  = (int*)(ws + WS_WL);
    float* BASE = ws + WS_BASE;
    unsigned long long* MASKS = (unsigned long long*)X3B;
    int* AUXI = (int*)(ws + WS_X3 + 330000);
    int* CNT = AUXI;           // 625
    int* OFF = AUXI + 640;     // 626
    int* CHOFF = AUXI + 1280;  // 626
    int* NWORK = AUXI + 1920;  // 1
    unsigned short* LIST = (unsigned short*)RA;
    float* COL = RB;
    float* ngp = out + (size_t)NPXB*OUTC;

    cam_consts_kernel<<<1, 64, 0, stream>>>(rot, tr, intr, prot, ptr_, CAM);
    (void)hipMemsetAsync(RA, 0, (size_t)SZA*sizeof(float), stream);
    (void)hipMemsetAsync(RB, 0, (size_t)SZA*sizeof(float), stream);
    pad_input_kernel<<<NCAM*FC*NPIX/256, 256, 0, stream>>>(img, RA);
    // conv1: RA -> RB (BN+ReLU fused); conv2: RB -> RA (borders still zero)
    conv3x3_sk_kernel<<<dim3(NCAM,32,3), 512, 0, stream>>>(RA, RB, c1w, c1b, b1g, b1b, b1m, b1v);
    conv3x3_sk_kernel<<<dim3(NCAM,32,3), 512, 0, stream>>>(RB, RA, c2w, c2b, b2g, b2b, b2m, b2v);
    conv1x1_kernel<<<dim3(NCAM,11,22), 256, 0, stream>>>(RA, X3B, COL, c3w, c3b);
    (void)hipMemsetAsync(ngp, 0, sizeof(float), stream);
    (void)hipMemsetAsync(out, 0, (size_t)NPXB*OUTC*sizeof(float), stream);
    moments_kernel<<<GTOT/256, 256, 0, stream>>>(X3B, CAM, GS, ngp);
    // X3 planes dead -> masks + aux live there
    (void)hipMemsetAsync(MASKS, 0, (size_t)NTILE*NTILE*NWORD*sizeof(unsigned long long), stream);
    build_masks_kernel<<<GTOT/256, 256, 0, stream>>>(GS, MASKS);
    cnt_kernel<<<NTILE*NTILE, 256, 0, stream>>>(MASKS, CNT);
    scan_kernel<<<1, 640, 0, stream>>>(CNT, OFF, CHOFF, NWORK);
    fill_kernel<<<NTILE*NTILE, 256, 0, stream>>>(MASKS, CNT, OFF, CHOFF, LIST, WL);
    chunk_sums_kernel<<<8192, 256, 0, stream>>>(GS, LIST, CNT, OFF, WL, NWORK, BASE);
    chunk_prefix_kernel<<<NTILE*NTILE, 256, 0, stream>>>(CHOFF, BASE);
    composite_kernel<<<CBLK, 256, 0, stream>>>(GS, COL, LIST, CNT, OFF, WL, NWORK, BASE, out);
}

// Round 13
// 483.636 us; speedup vs baseline: 1.5301x; 1.5301x over previous
//
#include <hip/hip_runtime.h>

#define NCAM 6
#define FC   128
#define FH_  32
#define FW_  88
#define NPIX (FH_*FW_)        // 2816
#define PH   34
#define PW   92               // padded width (mult of 4 -> float4-aligned rows)
#define PPIX (PH*PW)          // 3128
#define ND   41
#define X3D  42               // 41 depth + 1 opacity planes
#define OUTC 128
#define GTOT (NCAM*NPIX)      // 16896
#define BEVH 100
#define BEVW 100
#define NPXB (BEVH*BEVW)      // 10000
#define NTILE 25              // 25x25 tiles of 4x4 px
#define NWORD 264             // 16896/64 mask words per tile
#define WCAP  70000           // worklist capacity (chunks)
#define CSIZE 64              // hits per chunk
#define CBLK  2048            // composite blocks (contiguous chunk ranges)

// ---- ws layout (float offsets). Total ~6.84M floats = 27.4 MB ----
#define SZA     (NCAM*FC*PPIX)           // 2402304
#define WS_CAM  0
#define WS_A    256                      // IMGP -> X2P -> hit lists (ushort)
#define WS_RB   (WS_A  + SZA)            // X1P -> colors
#define WS_X3   (WS_RB + SZA)            // depth+opacity planes -> masks+aux
#define WS_GS   (WS_X3 + NCAM*X3D*NPIX)  // gauss params 16896*8
#define WS_WL   (WS_GS + GTOT*8)         // worklist ints
#define WS_BASE (WS_WL + WCAP)           // per-chunk per-px bases WCAP*16

__device__ inline void inv3x3(const float* m, float* o) {
    float a=m[0],b=m[1],c=m[2],d=m[3],e=m[4],f=m[5],g=m[6],h=m[7],i=m[8];
    float A=e*i-f*h, B=c*h-b*i, C=b*f-c*e;
    float Dd=f*g-d*i, E=a*i-c*g, F=c*d-a*f;
    float Gg=d*h-e*g, H=b*g-a*h, I=a*e-b*d;
    float r = 1.0f/(a*A + b*Dd + c*Gg);
    o[0]=A*r; o[1]=B*r; o[2]=C*r; o[3]=Dd*r; o[4]=E*r; o[5]=F*r;
    o[6]=Gg*r; o[7]=H*r; o[8]=I*r;
}

__global__ void cam_consts_kernel(const float* __restrict__ rot, const float* __restrict__ tr,
                                  const float* __restrict__ intr, const float* __restrict__ prot,
                                  const float* __restrict__ ptr_, float* __restrict__ cam) {
    int n = threadIdx.x;
    if (n >= NCAM) return;
    float M1[9], Ki[9];
    inv3x3(prot + n*9, M1);
    inv3x3(intr + n*9, Ki);
    const float* R = rot + n*9;
    float* c = cam + n*24;
    for (int i=0;i<9;i++) c[i] = M1[i];
    for (int i=0;i<3;i++) c[9+i] = ptr_[n*3+i];
    for (int i=0;i<3;i++)
        for (int j=0;j<3;j++)
            c[12+i*3+j] = R[i*3+0]*Ki[0+j] + R[i*3+1]*Ki[3+j] + R[i*3+2]*Ki[6+j];
    for (int i=0;i<3;i++) c[21+i] = tr[n*3+i];
}

__global__ __launch_bounds__(256) void pad_input_kernel(const float* __restrict__ src,
                                                        float* __restrict__ dst) {
    int idx = blockIdx.x*256 + threadIdx.x;
    int plane = idx / NPIX, px = idx - plane*NPIX;
    int y = px / FW_, x = px - y*FW_;
    dst[(size_t)plane*PPIX + (y+1)*PW + (x+1)] = src[idx];
}

// direct 3x3 conv + folded BN + ReLU, 4co x 4px/thread (144 FMA : 6 loads/ci)
// with EXPLICIT 1-deep ci prefetch: next window loads issue before this ci's
// FMAs, giving ~288 VALU cycles to cover the L2 latency. No LDS, no atomics.
__global__ __launch_bounds__(256) void conv3x3_pf_kernel(
        const float* __restrict__ in, float* __restrict__ out, const float* __restrict__ w,
        const float* __restrict__ cb, const float* __restrict__ bg, const float* __restrict__ bb,
        const float* __restrict__ bm, const float* __restrict__ bv) {
    const int n   = blockIdx.x;
    const int co0 = blockIdx.y * 4;
    const int qid = blockIdx.z * 256 + threadIdx.x;   // 0..767, 704 valid
    if (qid >= 704) return;
    const int y = qid / 22, x0 = (qid - y*22) * 4;
    float scale[4], shift[4];
    #pragma unroll
    for (int c=0;c<4;c++) {
        float s = bg[co0+c] * rsqrtf(bv[co0+c] + 1e-3f);
        scale[c] = s;
        shift[c] = (cb[co0+c] - bm[co0+c]) * s + bb[co0+c];
    }
    float acc[4][4] = {};
    const float* ip = in + (size_t)n*FC*PPIX + y*PW + x0;   // window top-left (padded)
    const float* wb = w + (size_t)co0*FC*9;
    // prefetch registers (ci=0 window)
    float4 p4[3]; float2 p2[3];
    #pragma unroll
    for (int r=0;r<3;r++) {
        p4[r] = *(const float4*)(ip + r*PW);
        p2[r] = *(const float2*)(ip + r*PW + 4);
    }
    for (int ci=0; ci<FC; ++ci) {
        float v[3][6];
        #pragma unroll
        for (int r=0;r<3;r++) {
            v[r][0]=p4[r].x; v[r][1]=p4[r].y; v[r][2]=p4[r].z; v[r][3]=p4[r].w;
            v[r][4]=p2[r].x; v[r][5]=p2[r].y;
        }
        if (ci + 1 < FC) {                      // issue next ci's loads NOW
            const float* ipn = ip + PPIX;
            #pragma unroll
            for (int r=0;r<3;r++) {
                p4[r] = *(const float4*)(ipn + r*PW);
                p2[r] = *(const float2*)(ipn + r*PW + 4);
            }
        }
        #pragma unroll
        for (int c=0;c<4;c++) {
            const float* wr = wb + (size_t)c*FC*9 + ci*9;   // wave-uniform -> s_load
            float w00=wr[0],w01=wr[1],w02=wr[2],w10=wr[3],w11=wr[4],
                  w12=wr[5],w20=wr[6],w21=wr[7],w22=wr[8];
            #pragma unroll
            for (int p=0;p<4;p++) {
                float a = acc[c][p];
                a = fmaf(w00, v[0][p], a); a = fmaf(w01, v[0][p+1], a); a = fmaf(w02, v[0][p+2], a);
                a = fmaf(w10, v[1][p], a); a = fmaf(w11, v[1][p+1], a); a = fmaf(w12, v[1][p+2], a);
                a = fmaf(w20, v[2][p], a); a = fmaf(w21, v[2][p+1], a); a = fmaf(w22, v[2][p+2], a);
                acc[c][p] = a;
            }
        }
        ip += PPIX;
    }
    const int po = (y+1)*PW + (x0+1);
    #pragma unroll
    for (int c=0;c<4;c++) {
        float* op = out + ((size_t)n*FC + co0 + c)*PPIX + po;
        #pragma unroll
        for (int p=0;p<4;p++)
            op[p] = fmaxf(fmaf(acc[c][p], scale[c], shift[c]), 0.0f);
    }
}

// 1x1 conv: grid (NCAM, 11 px-chunks, 22 co-groups of 8). acc[8] fully unrolled
// (stays in VGPRs), weights wave-uniform -> s_loads.
__global__ __launch_bounds__(256) void conv1x1_kernel(const float* __restrict__ in,
        float* __restrict__ x3d, float* __restrict__ colors,
        const float* __restrict__ w, const float* __restrict__ b) {
    const int n   = blockIdx.x;
    const int px  = blockIdx.y * 256 + threadIdx.x;
    const int co0 = blockIdx.z * 8;                  // 0..168
    const int y   = px / FW_, x = px - y*FW_;
    const int pp  = (y+1)*PW + (x+1);
    const float* wr[8];
    float acc[8];
    #pragma unroll
    for (int k=0;k<8;k++) {
        int co = min(co0 + k, 169);                  // clamp avoids OOB reads (stores guarded)
        wr[k]  = w + (size_t)co*FC;
        acc[k] = b[co];
    }
    const float* ip = in + (size_t)n*FC*PPIX + pp;
    #pragma unroll 4
    for (int ci=0; ci<FC; ++ci) {
        float v = ip[(size_t)ci*PPIX];
        #pragma unroll
        for (int k=0;k<8;k++) acc[k] = fmaf(wr[k][ci], v, acc[k]);
    }
    #pragma unroll
    for (int k=0;k<8;k++) {
        int co = co0 + k;
        if (co < X3D)
            x3d[((size_t)n*X3D + co)*NPIX + px] = acc[k];
        else if (co < 170)
            colors[(((size_t)(n*NPIX + px)) << 7) + (co - X3D)] = acc[k];
    }
}

// per-gaussian: softmax moments, splat params {my,mx,A,2B,C,qm,ri,rj}
__global__ __launch_bounds__(256) void moments_kernel(const float* __restrict__ x3,
        const float* __restrict__ cam, float* __restrict__ gauss, float* __restrict__ ng) {
    int gi = blockIdx.x*256 + threadIdx.x;
    int n  = gi / NPIX;
    int p  = gi - n*NPIX;
    int h  = p / FW_, xp = p - h*FW_;
    const float* cc = cam + n*24;
    float u = xp * (703.0f/87.0f);
    float v = h  * (255.0f/31.0f);
    float fx = u - cc[9], fy = v - cc[10], fz = -cc[11];
    float p0x = cc[0]*fx + cc[1]*fy + cc[2]*fz;
    float p0y = cc[3]*fx + cc[4]*fy + cc[5]*fz;
    float p0z = cc[6]*fx + cc[7]*fy + cc[8]*fz;
    const float* lg = x3 + (size_t)n*X3D*NPIX + p;

    float mxl = -1e30f;
    for (int d=0; d<ND; ++d) mxl = fmaxf(mxl, lg[(size_t)d*NPIX]);
    float s=0.f, sgx=0.f, sgy=0.f;
    for (int d=0; d<ND; ++d) {
        float e  = __expf(lg[(size_t)d*NPIX] - mxl);
        float dz = 4.0f + (float)d;
        float pz = p0z + dz*cc[8];
        float px = (p0x + dz*cc[2]) * pz;
        float py = (p0y + dz*cc[5]) * pz;
        float gx = cc[12]*px + cc[13]*py + cc[14]*pz + cc[21];
        float gy = cc[15]*px + cc[16]*py + cc[17]*pz + cc[22];
        s += e; sgx += e*gx; sgy += e*gy;
    }
    float inv_s = 1.0f/s;
    float mex = sgx*inv_s, mey = sgy*inv_s;
    float cxx=0.f, cxy=0.f, cyy=0.f;
    for (int d=0; d<ND; ++d) {
        float e  = __expf(lg[(size_t)d*NPIX] - mxl);
        float dz = 4.0f + (float)d;
        float pz = p0z + dz*cc[8];
        float px = (p0x + dz*cc[2]) * pz;
        float py = (p0y + dz*cc[5]) * pz;
        float gx = cc[12]*px + cc[13]*py + cc[14]*pz + cc[21];
        float gy = cc[15]*px + cc[16]*py + cc[17]*pz + cc[22];
        float dxv = gx - mex, dyv = gy - mey;
        cxx += e*dxv*dxv; cxy += e*dxv*dyv; cyy += e*dyv*dyv;
    }
    const float k9 = inv_s * (1.0f/9.0f);
    cxx *= k9; cxy *= k9; cyy *= k9;

    float lo = lg[(size_t)ND*NPIX];
    float op = 1.0f/(1.0f + __expf(-lo));
    bool mask = op > 0.05f;

    const float SC = 0.02f, SH = 50.0f, SW = 50.0f;
    float my = -SH*(mey*SC) + 50.0f;
    float mx = -SW*(mex*SC) + 50.0f;
    float a  = SH*SH*(cyy*SC*SC) + 0.3f;
    float b  = SH*SW*(cxy*SC*SC);
    float c  = SW*SW*(cxx*SC*SC) + 0.3f;
    float det = a*c - b*b;
    bool valid = mask && (det > 0.0f);
    float A, B2, C, qm, ri, rj;
    if (valid) {
        float idet = 1.0f/det;
        A = c*idet; B2 = -2.0f*b*idet; C = a*idet;
        qm = 2.0f*__logf(255.0f*op);
        ri = sqrtf(qm*a); rj = sqrtf(qm*c);
    } else { A=B2=C=0.f; qm=-1.0f; ri=-1e30f; rj=-1e30f; }
    float* gp = gauss + (size_t)gi*8;
    gp[0]=my; gp[1]=mx; gp[2]=A; gp[3]=B2; gp[4]=C; gp[5]=qm; gp[6]=ri; gp[7]=rj;

    unsigned long long bal = __ballot(mask);
    if ((threadIdx.x & 63) == 0) atomicAdd(ng, (float)__popcll(bal));
}

// exact per-row ellipse interval culling -> tile bitmasks
__global__ __launch_bounds__(256) void build_masks_kernel(const float* __restrict__ gauss,
        unsigned long long* __restrict__ masks) {
    const int g = blockIdx.x*256 + threadIdx.x;
    const float4 g0 = *(const float4*)(gauss + ((size_t)g << 3));      // my,mx,A,2B
    const float4 g1 = *(const float4*)(gauss + ((size_t)g << 3) + 4);  // C,qm,ri,rj
    if (g1.y < 0.0f) return;
    const float my = g0.x, mx = g0.y, A = g0.z, B = 0.5f*g0.w, C = g1.x, qm = g1.y, ri = g1.z;
    const float invC = 1.0f / C;
    const float k2 = C*A - B*B;          // > 0
    int ti0 = max(0, (int)floorf((my - ri) * 0.25f));
    int ti1 = min(NTILE-1, (int)floorf((my + ri) * 0.25f));
    const int wi = g >> 6;
    const unsigned long long bit = 1ull << (g & 63);
    for (int ti = ti0; ti <= ti1; ++ti) {
        float jmn = 1e30f, jmx = -1e30f;
        #pragma unroll
        for (int r = 0; r < 4; ++r) {
            int i = 4*ti + r;
            if (i < 0 || i > 99) continue;
            float di = (float)i - my;
            float disc = C*qm - k2*di*di;
            if (disc < 0.0f) continue;
            float sd = sqrtf(disc);
            float jc = -B*di;
            jmn = fminf(jmn, (jc - sd)*invC + mx);
            jmx = fmaxf(jmx, (jc + sd)*invC + mx);
        }
        if (jmx < jmn) continue;
        int jl = max(0, (int)ceilf(jmn));
        int jh = min(99, (int)floorf(jmx));
        if (jl > jh) continue;
        for (int tj = (jl >> 2); tj <= (jh >> 2); ++tj)
            atomicOr(&masks[(size_t)(ti*NTILE + tj)*NWORD + wi], bit);
    }
}

// per-tile hit count
__global__ __launch_bounds__(256) void cnt_kernel(const unsigned long long* __restrict__ masks,
                                                  int* __restrict__ cnt) {
    __shared__ int sc;
    const int tile = blockIdx.x, t = threadIdx.x;
    if (t == 0) sc = 0;
    __syncthreads();
    if (t < NWORD) atomicAdd(&sc, __popcll(masks[(size_t)tile*NWORD + t]));
    __syncthreads();
    if (t == 0) cnt[tile] = sc;
}

// parallel exclusive scans over 625 tiles (single 640-thread block, shfl scan)
__global__ __launch_bounds__(640) void scan_kernel(const int* __restrict__ cnt,
        int* __restrict__ off, int* __restrict__ choff, int* __restrict__ nwork) {
    __shared__ int wsum[16], wsum2[16];
    const int t = threadIdx.x;              // 0..639, 10 waves
    const int lane = t & 63, wv = t >> 6;
    int c  = (t < NTILE*NTILE) ? cnt[t] : 0;
    int ch = (c + CSIZE-1) >> 6;
    int v = c, v2 = ch;
    #pragma unroll
    for (int o = 1; o < 64; o <<= 1) {
        int u  = __shfl_up(v,  (unsigned)o, 64);
        int u2 = __shfl_up(v2, (unsigned)o, 64);
        if (lane >= o) { v += u; v2 += u2; }
    }
    if (lane == 63) { wsum[wv] = v; wsum2[wv] = v2; }
    __syncthreads();
    int pre = 0, pre2 = 0;
    for (int w2 = 0; w2 < wv; ++w2) { pre += wsum[w2]; pre2 += wsum2[w2]; }
    int inc = v + pre, inc2 = v2 + pre2;
    if (t < NTILE*NTILE) { off[t] = inc - c; choff[t] = inc2 - ch; }
    if (t == NTILE*NTILE - 1) {
        off[NTILE*NTILE] = inc;
        choff[NTILE*NTILE] = inc2;
        nwork[0] = (inc2 > WCAP) ? WCAP : inc2;
    }
}

// expand bitmasks -> dense ordered hit lists + chunk worklist
__global__ __launch_bounds__(256) void fill_kernel(const unsigned long long* __restrict__ masks,
        const int* __restrict__ cnt, const int* __restrict__ off, const int* __restrict__ choff,
        unsigned short* __restrict__ list, int* __restrict__ wl) {
    __shared__ unsigned long long sw[NWORD];
    __shared__ int wpre[NWORD];
    const int tile = blockIdx.x, t = threadIdx.x;
    if (t < NWORD) sw[t] = masks[(size_t)tile*NWORD + t];
    __syncthreads();
    if (t == 0) {
        int run = 0;
        for (int w2 = 0; w2 < NWORD; ++w2) { wpre[w2] = run; run += __popcll(sw[w2]); }
    }
    __syncthreads();
    if (t < NWORD) {
        unsigned long long m = sw[t];
        int pos = off[tile] + wpre[t], base = t << 6;
        while (m) { int b = __builtin_ctzll(m); m &= m - 1; list[pos++] = (unsigned short)(base + b); }
    }
    int nch = (cnt[tile] + CSIZE-1)/CSIZE;
    int c0 = choff[tile];
    if (t < nch && c0 + t < WCAP) wl[c0 + t] = (tile << 9) | t;
}

__device__ inline float eval_alpha(const float4 g0, const float4 g1, float fi, float fj) {
    float dI = fi - g0.x, dJ = fj - g0.y;
    float q = dI*(g0.z*dI + g0.w*dJ) + g1.x*dJ*dJ;     // g0.w = 2B
    if (q < 0.0f || q > g1.y) return 0.0f;
    return fminf(0.99f, 0.003921568627f * __expf(0.5f*(g1.y - q)));
}

// per chunk: per-px sums of log(1-alpha) -> BASE[e][px] (pre-prefix)
__global__ __launch_bounds__(256) void chunk_sums_kernel(const float* __restrict__ gauss,
        const unsigned short* __restrict__ list, const int* __restrict__ cnt,
        const int* __restrict__ off, const int* __restrict__ wl, const int* __restrict__ nwork,
        float* __restrict__ base) {
    const int nw = nwork[0];
    const int t = threadIdx.x;
    const int px = t & 15, kg = t >> 4;
    __shared__ unsigned short slist[CSIZE];
    __shared__ float red[16][17];
    for (int e = blockIdx.x; e < nw; e += gridDim.x) {
        int v = wl[e], tile = v >> 9, c = v & 511;
        int hbase = off[tile] + (c << 6);
        int nh = min(CSIZE, cnt[tile] - (c << 6));
        if (t < nh) slist[t] = list[hbase + t];
        __syncthreads();
        const int i0 = (tile / NTILE) * 4, j0 = (tile % NTILE) * 4;
        const float fi = (float)(i0 + (px >> 2)), fj = (float)(j0 + (px & 3));
        float s = 0.0f;
        for (int k = kg; k < nh; k += 16) {
            int g = slist[k];
            float4 g0 = *(const float4*)(gauss + ((size_t)g << 3));
            float4 g1 = *(const float4*)(gauss + ((size_t)g << 3) + 4);
            float a = eval_alpha(g0, g1, fi, fj);
            if (a > 0.0f) s += __logf(1.0f - a);
        }
        red[kg][px] = s;
        __syncthreads();
        if (t < 16) {
            float acc = 0.0f;
            #pragma unroll
            for (int k2 = 0; k2 < 16; ++k2) acc += red[k2][t];
            base[(size_t)e*16 + t] = acc;
        }
        __syncthreads();
    }
}

// per tile: exclusive prefix of chunk sums (in place) -> chunk-start log-T bases
__global__ __launch_bounds__(256) void chunk_prefix_kernel(const int* __restrict__ choff,
                                                           float* __restrict__ base) {
    __shared__ float part[16][17];
    const int tile = blockIdx.x, t = threadIdx.x;
    const int c0 = choff[tile], nch = choff[tile+1] - c0;
    if (nch == 0) return;
    const int px = t & 15, cg = t >> 4;
    const int L16 = (nch + 15) >> 4;
    const int a0 = cg*L16, a1 = min(nch, a0 + L16);
    float s = 0.0f;
    for (int c = a0; c < a1; ++c) s += base[(size_t)(c0 + c)*16 + px];
    part[cg][px] = s;
    __syncthreads();
    if (t < 16) {
        float run = 0.0f;
        #pragma unroll
        for (int k = 0; k < 16; ++k) { float tmp = part[k][t]; part[k][t] = run; run += tmp; }
    }
    __syncthreads();
    float run = part[cg][px];
    for (int c = a0; c < a1; ++c) {
        size_t idx = (size_t)(c0 + c)*16 + px;
        float tmp = base[idx];
        base[idx] = run;
        run += tmp;
    }
}

// split-phase composite over CONTIGUOUS chunk ranges; accumulators flushed to
// global atomics only on tile change (worklist is tile-major).
__global__ __launch_bounds__(256) void composite_kernel(const float* __restrict__ gauss,
        const float* __restrict__ colors, const unsigned short* __restrict__ list,
        const int* __restrict__ cnt, const int* __restrict__ off, const int* __restrict__ wl,
        const int* __restrict__ nwork, const float* __restrict__ base, float* __restrict__ out) {
    const int nw = nwork[0];
    const int t = threadIdx.x;
    const int lane = t & 63;
    const int e_px = t >> 4, e_kg = t & 15;      // eval mapping
    const int a_cs4 = t & 31, a_pxq = t >> 5;    // accum: 4 channels, 2 pixels
    __shared__ unsigned short slist[CSIZE];
    __shared__ float s_w[CSIZE][17];
    const int per = (nw + CBLK - 1) / CBLK;
    int e0 = blockIdx.x * per;
    if (e0 >= nw) return;
    int e1 = min(nw, e0 + per);

    float4 acc0 = make_float4(0.f,0.f,0.f,0.f);
    float4 acc1 = make_float4(0.f,0.f,0.f,0.f);
    int cur_tile = wl[e0] >> 9;
    int cur_i0 = (cur_tile / NTILE) * 4, cur_j0 = (cur_tile % NTILE) * 4;

    for (int e = e0; e < e1; ++e) {
        int v = wl[e], tile = v >> 9, c = v & 511;
        if (tile != cur_tile) {
            const int pix0 = (cur_i0 + (a_pxq >> 2)) * BEVW + cur_j0 + (a_pxq & 3);
            const int pix1 = pix0 + 2 * BEVW;
            float* op = out + (size_t)(a_cs4 << 2) * NPXB;
            atomicAdd(op + 0*NPXB + pix0, acc0.x); atomicAdd(op + 1*NPXB + pix0, acc0.y);
            atomicAdd(op + 2*NPXB + pix0, acc0.z); atomicAdd(op + 3*NPXB + pix0, acc0.w);
            atomicAdd(op + 0*NPXB + pix1, acc1.x); atomicAdd(op + 1*NPXB + pix1, acc1.y);
            atomicAdd(op + 2*NPXB + pix1, acc1.z); atomicAdd(op + 3*NPXB + pix1, acc1.w);
            acc0 = make_float4(0.f,0.f,0.f,0.f);
            acc1 = make_float4(0.f,0.f,0.f,0.f);
            cur_tile = tile;
            cur_i0 = (tile / NTILE) * 4; cur_j0 = (tile % NTILE) * 4;
        }
        int hbase = off[cur_tile] + (c << 6);
        int nh = min(CSIZE, cnt[cur_tile] - (c << 6));
        if (t < nh) slist[t] = list[hbase + t];
        __syncthreads();
        // ---- phase E: eval each (hit,px) once + 16-lane segmented scan ----
        {
            const float fi = (float)(cur_i0 + (e_px >> 2)), fj = (float)(cur_j0 + (e_px & 3));
            const int k0 = e_kg << 2;
            float a4[4]; float lsum = 0.0f;
            #pragma unroll
            for (int i = 0; i < 4; ++i) {
                int k = k0 + i;
                float a = 0.0f;
                if (k < nh) {
                    int g = slist[k];
                    float4 g0 = *(const float4*)(gauss + ((size_t)g << 3));
                    float4 g1 = *(const float4*)(gauss + ((size_t)g << 3) + 4);
                    a = eval_alpha(g0, g1, fi, fj);
                }
                a4[i] = a;
                if (a > 0.0f) lsum += __logf(1.0f - a);
            }
            float s = lsum;
            #pragma unroll
            for (int o = 1; o < 16; o <<= 1) {
                float u = __shfl_up(s, (unsigned)o, 64);
                if ((lane & 15) >= o) s += u;
            }
            float T = __expf(base[(size_t)e*16 + e_px] + (s - lsum));
            #pragma unroll
            for (int i = 0; i < 4; ++i) {
                float wv = a4[i] * T; T -= wv;
                s_w[k0 + i][e_px] = wv;
            }
        }
        __syncthreads();
        // ---- phase A: dependency-free accumulation into registers ----
        for (int k = 0; k < nh; ++k) {
            int g = slist[k];
            float w0 = s_w[k][a_pxq];
            float w1 = s_w[k][a_pxq + 8];
            float4 cl = *(const float4*)(colors + ((size_t)g << 7) + (a_cs4 << 2));
            acc0.x = fmaf(w0, cl.x, acc0.x); acc0.y = fmaf(w0, cl.y, acc0.y);
            acc0.z = fmaf(w0, cl.z, acc0.z); acc0.w = fmaf(w0, cl.w, acc0.w);
            acc1.x = fmaf(w1, cl.x, acc1.x); acc1.y = fmaf(w1, cl.y, acc1.y);
            acc1.z = fmaf(w1, cl.z, acc1.z); acc1.w = fmaf(w1, cl.w, acc1.w);
        }
        __syncthreads();
    }
    // final flush
    const int pix0 = (cur_i0 + (a_pxq >> 2)) * BEVW + cur_j0 + (a_pxq & 3);
    const int pix1 = pix0 + 2 * BEVW;
    float* op = out + (size_t)(a_cs4 << 2) * NPXB;
    atomicAdd(op + 0*NPXB + pix0, acc0.x); atomicAdd(op + 1*NPXB + pix0, acc0.y);
    atomicAdd(op + 2*NPXB + pix0, acc0.z); atomicAdd(op + 3*NPXB + pix0, acc0.w);
    atomicAdd(op + 0*NPXB + pix1, acc1.x); atomicAdd(op + 1*NPXB + pix1, acc1.y);
    atomicAdd(op + 2*NPXB + pix1, acc1.z); atomicAdd(op + 3*NPXB + pix1, acc1.w);
}

extern "C" void kernel_launch(void* const* d_in, const int* in_sizes, int n_in,
                              void* d_out, int out_size, void* d_ws, size_t ws_size,
                              hipStream_t stream) {
    const float* rot  = (const float*)d_in[0];
    const float* tr   = (const float*)d_in[1];
    const float* intr = (const float*)d_in[2];
    const float* prot = (const float*)d_in[3];
    const float* ptr_ = (const float*)d_in[4];
    const float* img  = (const float*)d_in[5];
    const float* c1w  = (const float*)d_in[6];  const float* c1b = (const float*)d_in[7];
    const float* b1g  = (const float*)d_in[8];  const float* b1b = (const float*)d_in[9];
    const float* b1m  = (const float*)d_in[10]; const float* b1v = (const float*)d_in[11];
    const float* c2w  = (const float*)d_in[12]; const float* c2b = (const float*)d_in[13];
    const float* b2g  = (const float*)d_in[14]; const float* b2b = (const float*)d_in[15];
    const float* b2m  = (const float*)d_in[16]; const float* b2v = (const float*)d_in[17];
    const float* c3w  = (const float*)d_in[18]; const float* c3b = (const float*)d_in[19];
    float* out = (float*)d_out;
    float* ws  = (float*)d_ws;
    float* CAM = ws + WS_CAM;
    float* RA  = ws + WS_A;    // IMGP -> X2P -> lists
    float* RB  = ws + WS_RB;   // X1P -> colors
    float* X3B = ws + WS_X3;   // planes -> masks+aux
    float* GS  = ws + WS_GS;
    int*   WL  = (int*)(ws + WS_WL);
    float* BASE = ws + WS_BASE;
    unsigned long long* MASKS = (unsigned long long*)X3B;
    int* AUXI = (int*)(ws + WS_X3 + 330000);
    int* CNT = AUXI;           // 625
    int* OFF = AUXI + 640;     // 626
    int* CHOFF = AUXI + 1280;  // 626
    int* NWORK = AUXI + 1920;  // 1
    unsigned short* LIST = (unsigned short*)RA;
    float* COL = RB;
    float* ngp = out + (size_t)NPXB*OUTC;

    cam_consts_kernel<<<1, 64, 0, stream>>>(rot, tr, intr, prot, ptr_, CAM);
    (void)hipMemsetAsync(RA, 0, (size_t)SZA*sizeof(float), stream);
    (void)hipMemsetAsync(RB, 0, (size_t)SZA*sizeof(float), stream);
    pad_input_kernel<<<NCAM*FC*NPIX/256, 256, 0, stream>>>(img, RA);
    // conv1: RA -> RB (BN+ReLU fused); conv2: RB -> RA (borders still zero)
    conv3x3_pf_kernel<<<dim3(NCAM,32,3), 256, 0, stream>>>(RA, RB, c1w, c1b, b1g, b1b, b1m, b1v);
    conv3x3_pf_kernel<<<dim3(NCAM,32,3), 256, 0, stream>>>(RB, RA, c2w, c2b, b2g, b2b, b2m, b2v);
    conv1x1_kernel<<<dim3(NCAM,11,22), 256, 0, stream>>>(RA, X3B, COL, c3w, c3b);
    (void)hipMemsetAsync(ngp, 0, sizeof(float), stream);
    (void)hipMemsetAsync(out, 0, (size_t)NPXB*OUTC*sizeof(float), stream);
    moments_kernel<<<GTOT/256, 256, 0, stream>>>(X3B, CAM, GS, ngp);
    // X3 planes dead -> masks + aux live there
    (void)hipMemsetAsync(MASKS, 0, (size_t)NTILE*NTILE*NWORD*sizeof(unsigned long long), stream);
    build_masks_kernel<<<GTOT/256, 256, 0, stream>>>(GS, MASKS);
    cnt_kernel<<<NTILE*NTILE, 256, 0, stream>>>(MASKS, CNT);
    scan_kernel<<<1, 640, 0, stream>>>(CNT, OFF, CHOFF, NWORK);
    fill_kernel<<<NTILE*NTILE, 256, 0, stream>>>(MASKS, CNT, OFF, CHOFF, LIST, WL);
    chunk_sums_kernel<<<8192, 256, 0, stream>>>(GS, LIST, CNT, OFF, WL, NWORK, BASE);
    chunk_prefix_kernel<<<NTILE*NTILE, 256, 0, stream>>>(CHOFF, BASE);
    composite_kernel<<<CBLK, 256, 0, stream>>>(GS, COL, LIST, CNT, OFF, WL, NWORK, BASE, out);
}

// Round 14
// 481.972 us; speedup vs baseline: 1.5354x; 1.0035x over previous
//
#include <hip/hip_runtime.h>

#define NCAM 6
#define FC   128
#define FH_  32
#define FW_  88
#define NPIX (FH_*FW_)        // 2816
#define PH   34
#define PW   92               // padded width (mult of 4 -> float4-aligned rows)
#define PPIX (PH*PW)          // 3128
#define ND   41
#define X3D  42               // 41 depth + 1 opacity planes
#define OUTC 128
#define GTOT (NCAM*NPIX)      // 16896
#define BEVH 100
#define BEVW 100
#define NPXB (BEVH*BEVW)      // 10000
#define NTILE 25              // 25x25 tiles of 4x4 px
#define NWORD 264             // 16896/64 mask words per tile
#define WCAP  70000           // worklist capacity (chunks)
#define CSIZE 64              // hits per chunk
#define CBLK  2048            // composite blocks (contiguous chunk ranges)

// ---- ws layout (float offsets). Total ~6.84M floats = 27.4 MB ----
#define SZA     (NCAM*FC*PPIX)           // 2402304
#define WS_CAM  0
#define WS_A    256                      // IMGP -> X2P -> hit lists (ushort)
#define WS_RB   (WS_A  + SZA)            // X1P -> colors
#define WS_X3   (WS_RB + SZA)            // depth+opacity planes -> masks+aux
#define WS_GS   (WS_X3 + NCAM*X3D*NPIX)  // gauss params 16896*8
#define WS_WL   (WS_GS + GTOT*8)         // worklist ints
#define WS_BASE (WS_WL + WCAP)           // per-chunk per-px bases WCAP*16

__device__ inline void inv3x3(const float* m, float* o) {
    float a=m[0],b=m[1],c=m[2],d=m[3],e=m[4],f=m[5],g=m[6],h=m[7],i=m[8];
    float A=e*i-f*h, B=c*h-b*i, C=b*f-c*e;
    float Dd=f*g-d*i, E=a*i-c*g, F=c*d-a*f;
    float Gg=d*h-e*g, H=b*g-a*h, I=a*e-b*d;
    float r = 1.0f/(a*A + b*Dd + c*Gg);
    o[0]=A*r; o[1]=B*r; o[2]=C*r; o[3]=Dd*r; o[4]=E*r; o[5]=F*r;
    o[6]=Gg*r; o[7]=H*r; o[8]=I*r;
}

__global__ void cam_consts_kernel(const float* __restrict__ rot, const float* __restrict__ tr,
                                  const float* __restrict__ intr, const float* __restrict__ prot,
                                  const float* __restrict__ ptr_, float* __restrict__ cam) {
    int n = threadIdx.x;
    if (n >= NCAM) return;
    float M1[9], Ki[9];
    inv3x3(prot + n*9, M1);
    inv3x3(intr + n*9, Ki);
    const float* R = rot + n*9;
    float* c = cam + n*24;
    for (int i=0;i<9;i++) c[i] = M1[i];
    for (int i=0;i<3;i++) c[9+i] = ptr_[n*3+i];
    for (int i=0;i<3;i++)
        for (int j=0;j<3;j++)
            c[12+i*3+j] = R[i*3+0]*Ki[0+j] + R[i*3+1]*Ki[3+j] + R[i*3+2]*Ki[6+j];
    for (int i=0;i<3;i++) c[21+i] = tr[n*3+i];
}

__global__ __launch_bounds__(256) void pad_input_kernel(const float* __restrict__ src,
                                                        float* __restrict__ dst) {
    int idx = blockIdx.x*256 + threadIdx.x;
    int plane = idx / NPIX, px = idx - plane*NPIX;
    int y = px / FW_, x = px - y*FW_;
    dst[(size_t)plane*PPIX + (y+1)*PW + (x+1)] = src[idx];
}

// direct 3x3 conv + folded BN + ReLU, 4co x 4px/thread (144 FMA : 6 loads/ci)
// with EXPLICIT 1-deep ci prefetch. No LDS, no atomics.
__global__ __launch_bounds__(256) void conv3x3_pf_kernel(
        const float* __restrict__ in, float* __restrict__ out, const float* __restrict__ w,
        const float* __restrict__ cb, const float* __restrict__ bg, const float* __restrict__ bb,
        const float* __restrict__ bm, const float* __restrict__ bv) {
    const int n   = blockIdx.x;
    const int co0 = blockIdx.y * 4;
    const int qid = blockIdx.z * 256 + threadIdx.x;   // 0..767, 704 valid
    if (qid >= 704) return;
    const int y = qid / 22, x0 = (qid - y*22) * 4;
    float scale[4], shift[4];
    #pragma unroll
    for (int c=0;c<4;c++) {
        float s = bg[co0+c] * rsqrtf(bv[co0+c] + 1e-3f);
        scale[c] = s;
        shift[c] = (cb[co0+c] - bm[co0+c]) * s + bb[co0+c];
    }
    float acc[4][4] = {};
    const float* ip = in + (size_t)n*FC*PPIX + y*PW + x0;
    const float* wb = w + (size_t)co0*FC*9;
    float4 p4[3]; float2 p2[3];
    #pragma unroll
    for (int r=0;r<3;r++) {
        p4[r] = *(const float4*)(ip + r*PW);
        p2[r] = *(const float2*)(ip + r*PW + 4);
    }
    for (int ci=0; ci<FC; ++ci) {
        float v[3][6];
        #pragma unroll
        for (int r=0;r<3;r++) {
            v[r][0]=p4[r].x; v[r][1]=p4[r].y; v[r][2]=p4[r].z; v[r][3]=p4[r].w;
            v[r][4]=p2[r].x; v[r][5]=p2[r].y;
        }
        if (ci + 1 < FC) {
            const float* ipn = ip + PPIX;
            #pragma unroll
            for (int r=0;r<3;r++) {
                p4[r] = *(const float4*)(ipn + r*PW);
                p2[r] = *(const float2*)(ipn + r*PW + 4);
            }
        }
        #pragma unroll
        for (int c=0;c<4;c++) {
            const float* wr = wb + (size_t)c*FC*9 + ci*9;
            float w00=wr[0],w01=wr[1],w02=wr[2],w10=wr[3],w11=wr[4],
                  w12=wr[5],w20=wr[6],w21=wr[7],w22=wr[8];
            #pragma unroll
            for (int p=0;p<4;p++) {
                float a = acc[c][p];
                a = fmaf(w00, v[0][p], a); a = fmaf(w01, v[0][p+1], a); a = fmaf(w02, v[0][p+2], a);
                a = fmaf(w10, v[1][p], a); a = fmaf(w11, v[1][p+1], a); a = fmaf(w12, v[1][p+2], a);
                a = fmaf(w20, v[2][p], a); a = fmaf(w21, v[2][p+1], a); a = fmaf(w22, v[2][p+2], a);
                acc[c][p] = a;
            }
        }
        ip += PPIX;
    }
    const int po = (y+1)*PW + (x0+1);
    #pragma unroll
    for (int c=0;c<4;c++) {
        float* op = out + ((size_t)n*FC + co0 + c)*PPIX + po;
        #pragma unroll
        for (int p=0;p<4;p++)
            op[p] = fmaxf(fmaf(acc[c][p], scale[c], shift[c]), 0.0f);
    }
}

// 1x1 conv: grid (NCAM, 11 px-chunks, 22 co-groups of 8)
__global__ __launch_bounds__(256) void conv1x1_kernel(const float* __restrict__ in,
        float* __restrict__ x3d, float* __restrict__ colors,
        const float* __restrict__ w, const float* __restrict__ b) {
    const int n   = blockIdx.x;
    const int px  = blockIdx.y * 256 + threadIdx.x;
    const int co0 = blockIdx.z * 8;
    const int y   = px / FW_, x = px - y*FW_;
    const int pp  = (y+1)*PW + (x+1);
    const float* wr[8];
    float acc[8];
    #pragma unroll
    for (int k=0;k<8;k++) {
        int co = min(co0 + k, 169);
        wr[k]  = w + (size_t)co*FC;
        acc[k] = b[co];
    }
    const float* ip = in + (size_t)n*FC*PPIX + pp;
    #pragma unroll 4
    for (int ci=0; ci<FC; ++ci) {
        float v = ip[(size_t)ci*PPIX];
        #pragma unroll
        for (int k=0;k<8;k++) acc[k] = fmaf(wr[k][ci], v, acc[k]);
    }
    #pragma unroll
    for (int k=0;k<8;k++) {
        int co = co0 + k;
        if (co < X3D)
            x3d[((size_t)n*X3D + co)*NPIX + px] = acc[k];
        else if (co < 170)
            colors[(((size_t)(n*NPIX + px)) << 7) + (co - X3D)] = acc[k];
    }
}

// per-gaussian: softmax moments, splat params {my,mx,A,2B,C,qm,ri,rj}
__global__ __launch_bounds__(256) void moments_kernel(const float* __restrict__ x3,
        const float* __restrict__ cam, float* __restrict__ gauss, float* __restrict__ ng) {
    int gi = blockIdx.x*256 + threadIdx.x;
    int n  = gi / NPIX;
    int p  = gi - n*NPIX;
    int h  = p / FW_, xp = p - h*FW_;
    const float* cc = cam + n*24;
    float u = xp * (703.0f/87.0f);
    float v = h  * (255.0f/31.0f);
    float fx = u - cc[9], fy = v - cc[10], fz = -cc[11];
    float p0x = cc[0]*fx + cc[1]*fy + cc[2]*fz;
    float p0y = cc[3]*fx + cc[4]*fy + cc[5]*fz;
    float p0z = cc[6]*fx + cc[7]*fy + cc[8]*fz;
    const float* lg = x3 + (size_t)n*X3D*NPIX + p;

    float mxl = -1e30f;
    for (int d=0; d<ND; ++d) mxl = fmaxf(mxl, lg[(size_t)d*NPIX]);
    float s=0.f, sgx=0.f, sgy=0.f;
    for (int d=0; d<ND; ++d) {
        float e  = __expf(lg[(size_t)d*NPIX] - mxl);
        float dz = 4.0f + (float)d;
        float pz = p0z + dz*cc[8];
        float px = (p0x + dz*cc[2]) * pz;
        float py = (p0y + dz*cc[5]) * pz;
        float gx = cc[12]*px + cc[13]*py + cc[14]*pz + cc[21];
        float gy = cc[15]*px + cc[16]*py + cc[17]*pz + cc[22];
        s += e; sgx += e*gx; sgy += e*gy;
    }
    float inv_s = 1.0f/s;
    float mex = sgx*inv_s, mey = sgy*inv_s;
    float cxx=0.f, cxy=0.f, cyy=0.f;
    for (int d=0; d<ND; ++d) {
        float e  = __expf(lg[(size_t)d*NPIX] - mxl);
        float dz = 4.0f + (float)d;
        float pz = p0z + dz*cc[8];
        float px = (p0x + dz*cc[2]) * pz;
        float py = (p0y + dz*cc[5]) * pz;
        float gx = cc[12]*px + cc[13]*py + cc[14]*pz + cc[21];
        float gy = cc[15]*px + cc[16]*py + cc[17]*pz + cc[22];
        float dxv = gx - mex, dyv = gy - mey;
        cxx += e*dxv*dxv; cxy += e*dxv*dyv; cyy += e*dyv*dyv;
    }
    const float k9 = inv_s * (1.0f/9.0f);
    cxx *= k9; cxy *= k9; cyy *= k9;

    float lo = lg[(size_t)ND*NPIX];
    float op = 1.0f/(1.0f + __expf(-lo));
    bool mask = op > 0.05f;

    const float SC = 0.02f, SH = 50.0f, SW = 50.0f;
    float my = -SH*(mey*SC) + 50.0f;
    float mx = -SW*(mex*SC) + 50.0f;
    float a  = SH*SH*(cyy*SC*SC) + 0.3f;
    float b  = SH*SW*(cxy*SC*SC);
    float c  = SW*SW*(cxx*SC*SC) + 0.3f;
    float det = a*c - b*b;
    bool valid = mask && (det > 0.0f);
    float A, B2, C, qm, ri, rj;
    if (valid) {
        float idet = 1.0f/det;
        A = c*idet; B2 = -2.0f*b*idet; C = a*idet;
        qm = 2.0f*__logf(255.0f*op);
        ri = sqrtf(qm*a); rj = sqrtf(qm*c);
    } else { A=B2=C=0.f; qm=-1.0f; ri=-1e30f; rj=-1e30f; }
    float* gp = gauss + (size_t)gi*8;
    gp[0]=my; gp[1]=mx; gp[2]=A; gp[3]=B2; gp[4]=C; gp[5]=qm; gp[6]=ri; gp[7]=rj;

    unsigned long long bal = __ballot(mask);
    if ((threadIdx.x & 63) == 0) atomicAdd(ng, (float)__popcll(bal));
}

// exact per-row ellipse interval culling -> tile bitmasks
__global__ __launch_bounds__(256) void build_masks_kernel(const float* __restrict__ gauss,
        unsigned long long* __restrict__ masks) {
    const int g = blockIdx.x*256 + threadIdx.x;
    const float4 g0 = *(const float4*)(gauss + ((size_t)g << 3));      // my,mx,A,2B
    const float4 g1 = *(const float4*)(gauss + ((size_t)g << 3) + 4);  // C,qm,ri,rj
    if (g1.y < 0.0f) return;
    const float my = g0.x, mx = g0.y, A = g0.z, B = 0.5f*g0.w, C = g1.x, qm = g1.y, ri = g1.z;
    const float invC = 1.0f / C;
    const float k2 = C*A - B*B;          // > 0
    int ti0 = max(0, (int)floorf((my - ri) * 0.25f));
    int ti1 = min(NTILE-1, (int)floorf((my + ri) * 0.25f));
    const int wi = g >> 6;
    const unsigned long long bit = 1ull << (g & 63);
    for (int ti = ti0; ti <= ti1; ++ti) {
        float jmn = 1e30f, jmx = -1e30f;
        #pragma unroll
        for (int r = 0; r < 4; ++r) {
            int i = 4*ti + r;
            if (i < 0 || i > 99) continue;
            float di = (float)i - my;
            float disc = C*qm - k2*di*di;
            if (disc < 0.0f) continue;
            float sd = sqrtf(disc);
            float jc = -B*di;
            jmn = fminf(jmn, (jc - sd)*invC + mx);
            jmx = fmaxf(jmx, (jc + sd)*invC + mx);
        }
        if (jmx < jmn) continue;
        int jl = max(0, (int)ceilf(jmn));
        int jh = min(99, (int)floorf(jmx));
        if (jl > jh) continue;
        for (int tj = (jl >> 2); tj <= (jh >> 2); ++tj)
            atomicOr(&masks[(size_t)(ti*NTILE + tj)*NWORD + wi], bit);
    }
}

// per-tile hit count
__global__ __launch_bounds__(256) void cnt_kernel(const unsigned long long* __restrict__ masks,
                                                  int* __restrict__ cnt) {
    __shared__ int sc;
    const int tile = blockIdx.x, t = threadIdx.x;
    if (t == 0) sc = 0;
    __syncthreads();
    if (t < NWORD) atomicAdd(&sc, __popcll(masks[(size_t)tile*NWORD + t]));
    __syncthreads();
    if (t == 0) cnt[tile] = sc;
}

// parallel exclusive scans over 625 tiles (single 640-thread block, shfl scan)
__global__ __launch_bounds__(640) void scan_kernel(const int* __restrict__ cnt,
        int* __restrict__ off, int* __restrict__ choff, int* __restrict__ nwork) {
    __shared__ int wsum[16], wsum2[16];
    const int t = threadIdx.x;
    const int lane = t & 63, wv = t >> 6;
    int c  = (t < NTILE*NTILE) ? cnt[t] : 0;
    int ch = (c + CSIZE-1) >> 6;
    int v = c, v2 = ch;
    #pragma unroll
    for (int o = 1; o < 64; o <<= 1) {
        int u  = __shfl_up(v,  (unsigned)o, 64);
        int u2 = __shfl_up(v2, (unsigned)o, 64);
        if (lane >= o) { v += u; v2 += u2; }
    }
    if (lane == 63) { wsum[wv] = v; wsum2[wv] = v2; }
    __syncthreads();
    int pre = 0, pre2 = 0;
    for (int w2 = 0; w2 < wv; ++w2) { pre += wsum[w2]; pre2 += wsum2[w2]; }
    int inc = v + pre, inc2 = v2 + pre2;
    if (t < NTILE*NTILE) { off[t] = inc - c; choff[t] = inc2 - ch; }
    if (t == NTILE*NTILE - 1) {
        off[NTILE*NTILE] = inc;
        choff[NTILE*NTILE] = inc2;
        nwork[0] = (inc2 > WCAP) ? WCAP : inc2;
    }
}

// expand bitmasks -> dense ordered hit lists + chunk worklist
__global__ __launch_bounds__(256) void fill_kernel(const unsigned long long* __restrict__ masks,
        const int* __restrict__ cnt, const int* __restrict__ off, const int* __restrict__ choff,
        unsigned short* __restrict__ list, int* __restrict__ wl) {
    __shared__ unsigned long long sw[NWORD];
    __shared__ int wpre[NWORD];
    const int tile = blockIdx.x, t = threadIdx.x;
    if (t < NWORD) sw[t] = masks[(size_t)tile*NWORD + t];
    __syncthreads();
    if (t == 0) {
        int run = 0;
        for (int w2 = 0; w2 < NWORD; ++w2) { wpre[w2] = run; run += __popcll(sw[w2]); }
    }
    __syncthreads();
    if (t < NWORD) {
        unsigned long long m = sw[t];
        int pos = off[tile] + wpre[t], base = t << 6;
        while (m) { int b = __builtin_ctzll(m); m &= m - 1; list[pos++] = (unsigned short)(base + b); }
    }
    int nch = (cnt[tile] + CSIZE-1)/CSIZE;
    int c0 = choff[tile];
    if (t < nch && c0 + t < WCAP) wl[c0 + t] = (tile << 9) | t;
}

__device__ inline float eval_alpha(const float4 g0, const float4 g1, float fi, float fj) {
    float dI = fi - g0.x, dJ = fj - g0.y;
    float q = dI*(g0.z*dI + g0.w*dJ) + g1.x*dJ*dJ;     // g0.w = 2B
    if (q < 0.0f || q > g1.y) return 0.0f;
    return fminf(0.99f, 0.003921568627f * __expf(0.5f*(g1.y - q)));
}

// per chunk: per-px sums of log(1-alpha) -> BASE[e][px] (pre-prefix)
__global__ __launch_bounds__(256) void chunk_sums_kernel(const float* __restrict__ gauss,
        const unsigned short* __restrict__ list, const int* __restrict__ cnt,
        const int* __restrict__ off, const int* __restrict__ wl, const int* __restrict__ nwork,
        float* __restrict__ base) {
    const int nw = nwork[0];
    const int t = threadIdx.x;
    const int px = t & 15, kg = t >> 4;
    __shared__ unsigned short slist[CSIZE];
    __shared__ float red[16][17];
    for (int e = blockIdx.x; e < nw; e += gridDim.x) {
        int v = wl[e], tile = v >> 9, c = v & 511;
        int hbase = off[tile] + (c << 6);
        int nh = min(CSIZE, cnt[tile] - (c << 6));
        if (t < nh) slist[t] = list[hbase + t];
        __syncthreads();
        const int i0 = (tile / NTILE) * 4, j0 = (tile % NTILE) * 4;
        const float fi = (float)(i0 + (px >> 2)), fj = (float)(j0 + (px & 3));
        float s = 0.0f;
        for (int k = kg; k < nh; k += 16) {
            int g = slist[k];
            float4 g0 = *(const float4*)(gauss + ((size_t)g << 3));
            float4 g1 = *(const float4*)(gauss + ((size_t)g << 3) + 4);
            float a = eval_alpha(g0, g1, fi, fj);
            if (a > 0.0f) s += __logf(1.0f - a);
        }
        red[kg][px] = s;
        __syncthreads();
        if (t < 16) {
            float acc = 0.0f;
            #pragma unroll
            for (int k2 = 0; k2 < 16; ++k2) acc += red[k2][t];
            base[(size_t)e*16 + t] = acc;
        }
        __syncthreads();
    }
}

// per tile: exclusive prefix of chunk sums (in place) -> chunk-start log-T bases
__global__ __launch_bounds__(256) void chunk_prefix_kernel(const int* __restrict__ choff,
                                                           float* __restrict__ base) {
    __shared__ float part[16][17];
    const int tile = blockIdx.x, t = threadIdx.x;
    const int c0 = choff[tile], nch = choff[tile+1] - c0;
    if (nch == 0) return;
    const int px = t & 15, cg = t >> 4;
    const int L16 = (nch + 15) >> 4;
    const int a0 = cg*L16, a1 = min(nch, a0 + L16);
    float s = 0.0f;
    for (int c = a0; c < a1; ++c) s += base[(size_t)(c0 + c)*16 + px];
    part[cg][px] = s;
    __syncthreads();
    if (t < 16) {
        float run = 0.0f;
        #pragma unroll
        for (int k = 0; k < 16; ++k) { float tmp = part[k][t]; part[k][t] = run; run += tmp; }
    }
    __syncthreads();
    float run = part[cg][px];
    for (int c = a0; c < a1; ++c) {
        size_t idx = (size_t)(c0 + c)*16 + px;
        float tmp = base[idx];
        base[idx] = run;
        run += tmp;
    }
}

// split-phase composite over CONTIGUOUS chunk ranges. v2: double-buffered
// slist (next chunk's list load issued during current compute) + static-bound
// unrolled phase A for full chunks (nh==64) so the compiler pipelines loads.
__global__ __launch_bounds__(256) void composite_kernel(const float* __restrict__ gauss,
        const float* __restrict__ colors, const unsigned short* __restrict__ list,
        const int* __restrict__ cnt, const int* __restrict__ off, const int* __restrict__ wl,
        const int* __restrict__ nwork, const float* __restrict__ base, float* __restrict__ out) {
    const int nw = nwork[0];
    const int t = threadIdx.x;
    const int lane = t & 63;
    const int e_px = t >> 4, e_kg = t & 15;      // eval mapping
    const int a_cs4 = t & 31, a_pxq = t >> 5;    // accum: 4 channels, 2 pixels
    __shared__ unsigned short slist[2][CSIZE];
    __shared__ float s_w[CSIZE][17];
    const int per = (nw + CBLK - 1) / CBLK;
    int e0 = blockIdx.x * per;
    if (e0 >= nw) return;
    int e1 = min(nw, e0 + per);

    float4 acc0 = make_float4(0.f,0.f,0.f,0.f);
    float4 acc1 = make_float4(0.f,0.f,0.f,0.f);
    int cur_tile = wl[e0] >> 9;
    int cur_i0 = (cur_tile / NTILE) * 4, cur_j0 = (cur_tile % NTILE) * 4;

    // prologue: load chunk e0's slist into buffer 0
    int buf = 0;
    {
        int v = wl[e0], tl = v >> 9, c = v & 511;
        int nh0 = min(CSIZE, cnt[tl] - (c << 6));
        if (t < nh0) slist[0][t] = list[off[tl] + (c << 6) + t];
    }

    for (int e = e0; e < e1; ++e) {
        int v = wl[e], tile = v >> 9, c = v & 511;
        if (tile != cur_tile) {
            const int pix0 = (cur_i0 + (a_pxq >> 2)) * BEVW + cur_j0 + (a_pxq & 3);
            const int pix1 = pix0 + 2 * BEVW;
            float* op = out + (size_t)(a_cs4 << 2) * NPXB;
            atomicAdd(op + 0*NPXB + pix0, acc0.x); atomicAdd(op + 1*NPXB + pix0, acc0.y);
            atomicAdd(op + 2*NPXB + pix0, acc0.z); atomicAdd(op + 3*NPXB + pix0, acc0.w);
            atomicAdd(op + 0*NPXB + pix1, acc1.x); atomicAdd(op + 1*NPXB + pix1, acc1.y);
            atomicAdd(op + 2*NPXB + pix1, acc1.z); atomicAdd(op + 3*NPXB + pix1, acc1.w);
            acc0 = make_float4(0.f,0.f,0.f,0.f);
            acc1 = make_float4(0.f,0.f,0.f,0.f);
            cur_tile = tile;
            cur_i0 = (tile / NTILE) * 4; cur_j0 = (tile % NTILE) * 4;
        }
        const int nh = min(CSIZE, cnt[cur_tile] - (c << 6));
        __syncthreads();   // slist[buf] ready; prev chunk's s_w reads done
        // issue next chunk's slist load into the other buffer
        if (e + 1 < e1) {
            int v2 = wl[e+1], tl2 = v2 >> 9, c2 = v2 & 511;
            int nh2 = min(CSIZE, cnt[tl2] - (c2 << 6));
            if (t < nh2) slist[buf^1][t] = list[off[tl2] + (c2 << 6) + t];
        }
        // ---- phase E: eval each (hit,px) once + 16-lane segmented scan ----
        {
            const float fi = (float)(cur_i0 + (e_px >> 2)), fj = (float)(cur_j0 + (e_px & 3));
            const int k0 = e_kg << 2;
            float a4[4]; float lsum = 0.0f;
            #pragma unroll
            for (int i = 0; i < 4; ++i) {
                int k = k0 + i;
                float a = 0.0f;
                if (k < nh) {
                    int g = slist[buf][k];
                    float4 g0 = *(const float4*)(gauss + ((size_t)g << 3));
                    float4 g1 = *(const float4*)(gauss + ((size_t)g << 3) + 4);
                    a = eval_alpha(g0, g1, fi, fj);
                }
                a4[i] = a;
                if (a > 0.0f) lsum += __logf(1.0f - a);
            }
            float s = lsum;
            #pragma unroll
            for (int o = 1; o < 16; o <<= 1) {
                float u = __shfl_up(s, (unsigned)o, 64);
                if ((lane & 15) >= o) s += u;
            }
            float T = __expf(base[(size_t)e*16 + e_px] + (s - lsum));
            #pragma unroll
            for (int i = 0; i < 4; ++i) {
                float wv = a4[i] * T; T -= wv;
                s_w[k0 + i][e_px] = wv;
            }
        }
        __syncthreads();   // s_w ready
        // ---- phase A: dependency-free accumulation (static fast path) ----
        const float* colbase = colors;
        if (nh == CSIZE) {
            #pragma unroll 8
            for (int k = 0; k < CSIZE; ++k) {
                int g = slist[buf][k];
                float w0 = s_w[k][a_pxq];
                float w1 = s_w[k][a_pxq + 8];
                float4 cl = *(const float4*)(colbase + ((size_t)g << 7) + (a_cs4 << 2));
                acc0.x = fmaf(w0, cl.x, acc0.x); acc0.y = fmaf(w0, cl.y, acc0.y);
                acc0.z = fmaf(w0, cl.z, acc0.z); acc0.w = fmaf(w0, cl.w, acc0.w);
                acc1.x = fmaf(w1, cl.x, acc1.x); acc1.y = fmaf(w1, cl.y, acc1.y);
                acc1.z = fmaf(w1, cl.z, acc1.z); acc1.w = fmaf(w1, cl.w, acc1.w);
            }
        } else {
            #pragma unroll 4
            for (int k = 0; k < nh; ++k) {
                int g = slist[buf][k];
                float w0 = s_w[k][a_pxq];
                float w1 = s_w[k][a_pxq + 8];
                float4 cl = *(const float4*)(colbase + ((size_t)g << 7) + (a_cs4 << 2));
                acc0.x = fmaf(w0, cl.x, acc0.x); acc0.y = fmaf(w0, cl.y, acc0.y);
                acc0.z = fmaf(w0, cl.z, acc0.z); acc0.w = fmaf(w0, cl.w, acc0.w);
                acc1.x = fmaf(w1, cl.x, acc1.x); acc1.y = fmaf(w1, cl.y, acc1.y);
                acc1.z = fmaf(w1, cl.z, acc1.z); acc1.w = fmaf(w1, cl.w, acc1.w);
            }
        }
        buf ^= 1;
    }
    // final flush
    const int pix0 = (cur_i0 + (a_pxq >> 2)) * BEVW + cur_j0 + (a_pxq & 3);
    const int pix1 = pix0 + 2 * BEVW;
    float* op = out + (size_t)(a_cs4 << 2) * NPXB;
    atomicAdd(op + 0*NPXB + pix0, acc0.x); atomicAdd(op + 1*NPXB + pix0, acc0.y);
    atomicAdd(op + 2*NPXB + pix0, acc0.z); atomicAdd(op + 3*NPXB + pix0, acc0.w);
    atomicAdd(op + 0*NPXB + pix1, acc1.x); atomicAdd(op + 1*NPXB + pix1, acc1.y);
    atomicAdd(op + 2*NPXB + pix1, acc1.z); atomicAdd(op + 3*NPXB + pix1, acc1.w);
}

extern "C" void kernel_launch(void* const* d_in, const int* in_sizes, int n_in,
                              void* d_out, int out_size, void* d_ws, size_t ws_size,
                              hipStream_t stream) {
    const float* rot  = (const float*)d_in[0];
    const float* tr   = (const float*)d_in[1];
    const float* intr = (const float*)d_in[2];
    const float* prot = (const float*)d_in[3];
    const float* ptr_ = (const float*)d_in[4];
    const float* img  = (const float*)d_in[5];
    const float* c1w  = (const float*)d_in[6];  const float* c1b = (const float*)d_in[7];
    const float* b1g  = (const float*)d_in[8];  const float* b1b = (const float*)d_in[9];
    const float* b1m  = (const float*)d_in[10]; const float* b1v = (const float*)d_in[11];
    const float* c2w  = (const float*)d_in[12]; const float* c2b = (const float*)d_in[13];
    const float* b2g  = (const float*)d_in[14]; const float* b2b = (const float*)d_in[15];
    const float* b2m  = (const float*)d_in[16]; const float* b2v = (const float*)d_in[17];
    const float* c3w  = (const float*)d_in[18]; const float* c3b = (const float*)d_in[19];
    float* out = (float*)d_out;
    float* ws  = (float*)d_ws;
    float* CAM = ws + WS_CAM;
    float* RA  = ws + WS_A;    // IMGP -> X2P -> lists
    float* RB  = ws + WS_RB;   // X1P -> colors
    float* X3B = ws + WS_X3;   // planes -> masks+aux
    float* GS  = ws + WS_GS;
    int*   WL  = (int*)(ws + WS_WL);
    float* BASE = ws + WS_BASE;
    unsigned long long* MASKS = (unsigned long long*)X3B;
    int* AUXI = (int*)(ws + WS_X3 + 330000);
    int* CNT = AUXI;           // 625
    int* OFF = AUXI + 640;     // 626
    int* CHOFF = AUXI + 1280;  // 626
    int* NWORK = AUXI + 1920;  // 1
    unsigned short* LIST = (unsigned short*)RA;
    float* COL = RB;
    float* ngp = out + (size_t)NPXB*OUTC;

    cam_consts_kernel<<<1, 64, 0, stream>>>(rot, tr, intr, prot, ptr_, CAM);
    (void)hipMemsetAsync(RA, 0, (size_t)SZA*sizeof(float), stream);
    (void)hipMemsetAsync(RB, 0, (size_t)SZA*sizeof(float), stream);
    pad_input_kernel<<<NCAM*FC*NPIX/256, 256, 0, stream>>>(img, RA);
    conv3x3_pf_kernel<<<dim3(NCAM,32,3), 256, 0, stream>>>(RA, RB, c1w, c1b, b1g, b1b, b1m, b1v);
    conv3x3_pf_kernel<<<dim3(NCAM,32,3), 256, 0, stream>>>(RB, RA, c2w, c2b, b2g, b2b, b2m, b2v);
    conv1x1_kernel<<<dim3(NCAM,11,22), 256, 0, stream>>>(RA, X3B, COL, c3w, c3b);
    (void)hipMemsetAsync(ngp, 0, sizeof(float), stream);
    (void)hipMemsetAsync(out, 0, (size_t)NPXB*OUTC*sizeof(float), stream);
    moments_kernel<<<GTOT/256, 256, 0, stream>>>(X3B, CAM, GS, ngp);
    (void)hipMemsetAsync(MASKS, 0, (size_t)NTILE*NTILE*NWORD*sizeof(unsigned long long), stream);
    build_masks_kernel<<<GTOT/256, 256, 0, stream>>>(GS, MASKS);
    cnt_kernel<<<NTILE*NTILE, 256, 0, stream>>>(MASKS, CNT);
    scan_kernel<<<1, 640, 0, stream>>>(CNT, OFF, CHOFF, NWORK);
    fill_kernel<<<NTILE*NTILE, 256, 0, stream>>>(MASKS, CNT, OFF, CHOFF, LIST, WL);
    chunk_sums_kernel<<<8192, 256, 0, stream>>>(GS, LIST, CNT, OFF, WL, NWORK, BASE);
    chunk_prefix_kernel<<<NTILE*NTILE, 256, 0, stream>>>(CHOFF, BASE);
    composite_kernel<<<CBLK, 256, 0, stream>>>(GS, COL, LIST, CNT, OFF, WL, NWORK, BASE, out);
}